// Round 5
// baseline (116.773 us; speedup 1.0000x reference)
//
#include <hip/hip_runtime.h>

// ParallelRetention  B=4 S=4096 F=128  gamma=0.96875
// R4b: (compile fix: hand-rolled RNE bf16 pack, no __hip_bfloat162 bit_cast)
//     KbF fragment-ordered (no K LDS staging in retention; K loads overlap
//     prev chunk's PV in the barrier-free region); window 512->384;
//     proj: direct-from-global A-frags (no x stage), merged Q/K transpose.
//     Fixed ~45us harness d_ws poison fill dominates dur_us.

#define S_LEN 4096
#define B_N   4
#define F_N   128
#define WIN   384
#define LOG2_GAMMA (-0.0458036905705339f)

typedef unsigned short u16;
typedef unsigned int   u32;
typedef __attribute__((ext_vector_type(8))) short bf16x8;   // 8 bf16 (4 VGPRs)
typedef __attribute__((ext_vector_type(4))) float f32x4;

__device__ inline u16 f2bf(float x) {                   // RNE f32 -> bf16
    u32 u = __builtin_bit_cast(u32, x);
    u32 r = (u + 0x7fffu + ((u >> 16) & 1u)) >> 16;
    return (u16)r;
}
__device__ inline u32 pkbf(float a, float b) {          // packed RNE convert
    return (u32)f2bf(a) | ((u32)f2bf(b) << 16);
}

// ---------------------------------------------------------------------------
// prep: W[3][128][128] fp32 -> WbF bf16 B-fragment order.
// WbF[fragid][lane*8+j] = W[mat][nt*16+(lane&15)][ks*32+(lane>>4)*8+j],
// fragid = mat*32 + nt*4 + ks.  grid 24 x 256.
__global__ void prep_kernel(const float* __restrict__ Wq,
                            const float* __restrict__ Wk,
                            const float* __restrict__ Wv,
                            u16* __restrict__ WbF)
{
    const int idx    = blockIdx.x * 256 + threadIdx.x;   // 0..6143
    const int lane   = idx & 63;
    const int fragid = idx >> 6;                         // 0..95
    const int ks     = fragid & 3;
    const int nt     = (fragid >> 2) & 7;
    const int mat    = fragid >> 5;
    const float* W = (mat == 0) ? Wq : (mat == 1 ? Wk : Wv);
    const float* src = W + (nt * 16 + (lane & 15)) * F_N + ks * 32 + (lane >> 4) * 8;
    float4 a = *(const float4*)src;
    float4 b = *(const float4*)(src + 4);
    uint4 v = make_uint4(pkbf(a.x, a.y), pkbf(a.z, a.w),
                         pkbf(b.x, b.y), pkbf(b.z, b.w));
    *(uint4*)(WbF + fragid * 512 + lane * 8) = v;
}

// ---------------------------------------------------------------------------
// proj: grid 512 x 256 (4 waves). Block = 32 rows. wave w: mt=w&1, nh=w>>1.
// Outputs (all bf16, MFMA fragment order):
//   QbF/KbF[b][g=s>>4][ks 0..7][lane*8+j]   (k-dim = 256 = [cos|sin]x128)
//   VtF[b][tb=s>>5][ft 0..7][lane*8+j]      (k-dim = t within 32-block)
__global__ __launch_bounds__(256)
void proj_kernel(const float* __restrict__ x, const u16* __restrict__ WbF,
                 const float* __restrict__ bq, const float* __restrict__ bk,
                 const float* __restrict__ bv, const float* __restrict__ theta,
                 u16* __restrict__ QbF, u16* __restrict__ KbF,
                 u16* __restrict__ VtF)
{
    __shared__ __align__(16) u16 obQ[32 * 264];   // [row][256+8]; V reuses [128][40]
    __shared__ __align__(16) u16 obK[32 * 264];

    const int tid  = threadIdx.x;
    const int lane = tid & 63;
    const int w    = __builtin_amdgcn_readfirstlane(tid >> 6);
    const int r0   = blockIdx.x * 32;
    const int b    = r0 >> 12;
    const int s0   = r0 & (S_LEN - 1);
    const int col  = lane & 15;
    const int quad = lane >> 4;
    const int mt   = w & 1;
    const int nh   = w >> 1;

    // ---- A-frags direct from global x (fp32 -> packed bf16) ----
    bf16x8 af[4];
    const float* xr = x + (r0 + mt * 16 + col) * F_N + quad * 8;
#pragma unroll
    for (int ks = 0; ks < 4; ++ks) {
        float4 a = *(const float4*)(xr + ks * 32);
        float4 c = *(const float4*)(xr + ks * 32 + 4);
        uint4 u = make_uint4(pkbf(a.x, a.y), pkbf(a.z, a.w),
                             pkbf(c.x, c.y), pkbf(c.z, c.w));
        af[ks] = __builtin_bit_cast(bf16x8, u);
    }

    // ---- MFMA: q, k, v ----
    f32x4 qa[4], ka[4], va[4];
#pragma unroll
    for (int nt = 0; nt < 4; ++nt) {
        qa[nt] = (f32x4){0.f, 0.f, 0.f, 0.f};
        ka[nt] = (f32x4){0.f, 0.f, 0.f, 0.f};
        va[nt] = (f32x4){0.f, 0.f, 0.f, 0.f};
    }
#pragma unroll
    for (int nt = 0; nt < 4; ++nt) {
        const int ng = nh * 4 + nt;
#pragma unroll
        for (int ks = 0; ks < 4; ++ks) {
            bf16x8 bqf = *(const bf16x8*)(WbF + ((0 * 8 + ng) * 4 + ks) * 512 + lane * 8);
            bf16x8 bkf = *(const bf16x8*)(WbF + ((1 * 8 + ng) * 4 + ks) * 512 + lane * 8);
            bf16x8 bvf = *(const bf16x8*)(WbF + ((2 * 8 + ng) * 4 + ks) * 512 + lane * 8);
            qa[nt] = __builtin_amdgcn_mfma_f32_16x16x32_bf16(af[ks], bqf, qa[nt], 0, 0, 0);
            ka[nt] = __builtin_amdgcn_mfma_f32_16x16x32_bf16(af[ks], bkf, ka[nt], 0, 0, 0);
            va[nt] = __builtin_amdgcn_mfma_f32_16x16x32_bf16(af[ks], bvf, va[nt], 0, 0, 0);
        }
    }

    // ---- Q', K' -> obQ/obK (one pass, per-nt to limit liveness) ----
#pragma unroll
    for (int nt = 0; nt < 4; ++nt) {
        const int o = nh * 64 + nt * 16 + col;
        const float bqv = bq[o], bkv = bk[o], th = theta[o];
#pragma unroll
        for (int r = 0; r < 4; ++r) {
            const int srow = s0 + mt * 16 + quad * 4 + r;
            float sn, cs;
            __sincosf((float)(srow + 1) * th, &sn, &cs);
            const float q = qa[nt][r] + bqv;
            const float k = ka[nt][r] + bkv;
            const int row = mt * 16 + quad * 4 + r;
            obQ[row * 264 + o]       = f2bf(q * cs);
            obQ[row * 264 + 128 + o] = f2bf(q * sn);
            obK[row * 264 + o]       = f2bf(k * cs);
            obK[row * 264 + 128 + o] = f2bf(k * sn);
        }
    }
    __syncthreads();
#pragma unroll
    for (int it = 0; it < 4; ++it) {
        const int c  = it * 256 + tid;           // 0..1023
        const int gl = c >> 9;                   // 0..1
        const int ks = (c >> 6) & 7;
        const int ln = c & 63;
        const int a  = (gl * 16 + (ln & 15)) * 264 + ks * 32 + (ln >> 4) * 8;
        const long dst = (long)((b * 256 + (s0 >> 4) + gl) * 8 + ks) * 512 + ln * 8;
        *(uint4*)(QbF + dst) = *(const uint4*)(obQ + a);
        *(uint4*)(KbF + dst) = *(const uint4*)(obK + a);
    }
    __syncthreads();

    // ---- V -> obQ[f][40] -> VtF ----
#pragma unroll
    for (int nt = 0; nt < 4; ++nt) {
        const int f = nh * 64 + nt * 16 + col;
        const float bvv = bv[f];
#pragma unroll
        for (int r = 0; r < 4; ++r) {
            const int sl = mt * 16 + quad * 4 + r;
            obQ[f * 40 + sl] = f2bf(va[nt][r] + bvv);
        }
    }
    __syncthreads();
#pragma unroll
    for (int it = 0; it < 2; ++it) {
        const int c  = it * 256 + tid;           // 0..511
        const int ft = c >> 6;                   // 0..7
        const int ln = c & 63;
        uint4 v = *(const uint4*)(obQ + (ft * 16 + (ln & 15)) * 40 + (ln >> 4) * 8);
        *(uint4*)(VtF + ((long)((b * 128 + (s0 >> 5)) * 8 + ft)) * 512 + ln * 8) = v;
    }
}

// ---------------------------------------------------------------------------
// retention: grid (128, 4) x 256 (4 waves). s-tile 32, t-chunk 64.
// wave w: ssub=(w&1)*16, fh=w>>1. K/V frags direct from global (L2);
// only P round-trips LDS. 2 barriers/chunk; K-loads+P-MFMA of chunk ch
// share a barrier-free region with PV of chunk ch-1.
__global__ __launch_bounds__(256)
void retention_kernel(const u16* __restrict__ QbF, const u16* __restrict__ KbF,
                      const u16* __restrict__ VtF, float* __restrict__ out)
{
    __shared__ __align__(16) u16 P_lds[32 * 72];   // [s][64+8]

    const int tid  = threadIdx.x;
    const int lane = tid & 63;
    const int w    = __builtin_amdgcn_readfirstlane(tid >> 6);
    const int b    = blockIdx.y;
    const int s0   = blockIdx.x * 32;
    const int col  = lane & 15;
    const int quad = lane >> 4;
    const int ssub = (w & 1) * 16;
    const int fh   = w >> 1;

    const int t_start = (s0 >= WIN) ? ((s0 - WIN) & ~63) : 0;
    const int nch     = (s0 + 32 - t_start + 63) >> 6;

    // Q A-frags (coalesced, fragment-ordered)
    const int g = (s0 + ssub) >> 4;
    bf16x8 qf[8];
#pragma unroll
    for (int ks = 0; ks < 8; ++ks)
        qf[ks] = *(const bf16x8*)(QbF + ((long)((b * 256 + g) * 8 + ks)) * 512 + lane * 8);

    f32x4 oacc[4];
#pragma unroll
    for (int ft = 0; ft < 4; ++ft) oacc[ft] = (f32x4){0.f, 0.f, 0.f, 0.f};

    for (int ch = 0; ch < nch; ++ch) {
        const int tc = t_start + (ch << 6);

        // ---- P = Q'K'^T (K frags direct from global) ----
        f32x4 pacc[2];
#pragma unroll
        for (int tp = 0; tp < 2; ++tp) {
            const int tg = (tc >> 4) + fh * 2 + tp;
            const u16* kb = KbF + ((long)(b * 256 + tg) * 8) * 512 + lane * 8;
            f32x4 acc = (f32x4){0.f, 0.f, 0.f, 0.f};
#pragma unroll
            for (int ks = 0; ks < 8; ++ks) {
                bf16x8 kf = *(const bf16x8*)(kb + ks * 512);
                acc = __builtin_amdgcn_mfma_f32_16x16x32_bf16(qf[ks], kf, acc, 0, 0, 0);
            }
            pacc[tp] = acc;
        }
        __syncthreads();   // A: all waves done reading prev chunk's P_lds

        // ---- decay + causal mask -> P_lds bf16 ----
#pragma unroll
        for (int tp = 0; tp < 2; ++tp) {
            const int tglob = tc + (fh * 2 + tp) * 16 + col;
#pragma unroll
            for (int r = 0; r < 4; ++r) {
                const int e = (s0 + ssub + quad * 4 + r) - tglob;
                const float d = (e >= 0) ? exp2f((float)e * LOG2_GAMMA) : 0.f;
                P_lds[(ssub + quad * 4 + r) * 72 + (fh * 2 + tp) * 16 + col] =
                    f2bf(pacc[tp][r] * d);
            }
        }
        __syncthreads();   // B: P ready

        // ---- O += P V (V frags direct from global) ----
#pragma unroll
        for (int ks = 0; ks < 2; ++ks) {
            bf16x8 pa = *(const bf16x8*)(P_lds + (ssub + col) * 72 + ks * 32 + quad * 8);
            const int tb = (tc >> 5) + ks;
#pragma unroll
            for (int ft = 0; ft < 4; ++ft) {
                bf16x8 vb = *(const bf16x8*)(VtF +
                    ((long)((b * 128 + tb) * 8 + fh * 4 + ft)) * 512 + lane * 8);
                oacc[ft] = __builtin_amdgcn_mfma_f32_16x16x32_bf16(pa, vb, oacc[ft], 0, 0, 0);
            }
        }
    }

    float* ob = out + ((b << 12) + s0) * F_N;
#pragma unroll
    for (int ft = 0; ft < 4; ++ft)
#pragma unroll
        for (int r = 0; r < 4; ++r)
            ob[(ssub + quad * 4 + r) * F_N + fh * 64 + ft * 16 + col] = oacc[ft][r];
}

// ---------------------------------------------------------------------------
extern "C" void kernel_launch(void* const* d_in, const int* in_sizes, int n_in,
                              void* d_out, int out_size, void* d_ws, size_t ws_size,
                              hipStream_t stream) {
    const float* x     = (const float*)d_in[0];
    const float* Wq    = (const float*)d_in[1];
    const float* bq    = (const float*)d_in[2];
    const float* Wk    = (const float*)d_in[3];
    const float* bk    = (const float*)d_in[4];
    const float* Wv    = (const float*)d_in[5];
    const float* bv    = (const float*)d_in[6];
    const float* theta = (const float*)d_in[7];
    float* out = (float*)d_out;

    u16* ws  = (u16*)d_ws;
    u16* QbF = ws;                       // 4,194,304 u16 (8 MiB)
    u16* KbF = ws + 4194304;             // 4,194,304 u16
    u16* VtF = ws + 8388608;             // 2,097,152 u16
    u16* WbF = ws + 10485760;            // 49,152 u16

    prep_kernel<<<24, 256, 0, stream>>>(Wq, Wk, Wv, WbF);
    proj_kernel<<<512, 256, 0, stream>>>(x, WbF, bq, bk, bv, theta, QbF, KbF, VtF);
    retention_kernel<<<dim3(128, B_N), 256, 0, stream>>>(QbF, KbF, VtF, out);
}